// Round 5
// baseline (227.278 us; speedup 1.0000x reference)
//
#include <hip/hip_runtime.h>
#include <hip/hip_bf16.h>

typedef __attribute__((ext_vector_type(8))) short short8;
typedef __attribute__((ext_vector_type(4))) float float4_t;

#define D_MODEL 1024
#define N_HEADS 16
#define HEAD_DIM 64
#define B_SZ 2
#define SEQ 2048
#define M_ROWS (B_SZ*SEQ)   // 4096
#define NQKV 3072
#define SC_LOG2E 0.18033688011112042f  // log2(e)/sqrt(HEAD_DIM)

__device__ __forceinline__ unsigned short f2bf(float f) {
  unsigned u = __float_as_uint(f);
  u += 0x7FFFu + ((u >> 16) & 1u);   // RNE
  return (unsigned short)(u >> 16);
}

// async global->LDS, 16B per lane. LDS base must be wave-uniform.
__device__ __forceinline__ void gl_lds16(const unsigned short* g, unsigned short* l) {
  __builtin_amdgcn_global_load_lds(
      (const __attribute__((address_space(1))) unsigned int*)(size_t)g,
      (__attribute__((address_space(3))) unsigned int*)(unsigned int)(size_t)l,
      16, 0, 0);
}

// ---- fused prep: x->bf16, Wp->bf16, Wq/Wk/Wv -> Wall [sel*1024+h*64+e][d] ----
__global__ void prep(const float* __restrict__ x, const float* __restrict__ Wp,
                     const float* __restrict__ Wq, const float* __restrict__ Wk,
                     const float* __restrict__ Wv,
                     unsigned short* __restrict__ xb, unsigned short* __restrict__ Wpb,
                     unsigned short* __restrict__ Wall) {
  __shared__ float t[16][17];
  int bid = blockIdx.x;
  if (bid < 5120) {
    const float* src; unsigned short* dst; int base;
    if (bid < 4096) { src = x;  dst = xb;  base = bid * 1024 + threadIdx.x * 4; }
    else            { src = Wp; dst = Wpb; base = (bid - 4096) * 1024 + threadIdx.x * 4; }
    float4 v = *(const float4*)(src + base);
    dst[base + 0] = f2bf(v.x);
    dst[base + 1] = f2bf(v.y);
    dst[base + 2] = f2bf(v.z);
    dst[base + 3] = f2bf(v.w);
  } else {
    int u = bid - 5120;
    int sel = u >> 12;
    u &= 4095;
    const float* W = sel == 0 ? Wq : (sel == 1 ? Wk : Wv);
    int d0 = (u & 63) * 16, e0 = ((u >> 6) & 3) * 16, hh = u >> 8;
    int tx = threadIdx.x & 15, ty = threadIdx.x >> 4;
    t[ty][tx] = W[hh * (D_MODEL * HEAD_DIM) + (d0 + ty) * HEAD_DIM + e0 + tx];
    __syncthreads();
    Wall[(size_t)(sel * 1024 + hh * 64 + e0 + ty) * D_MODEL + d0 + tx] = f2bf(t[tx][ty]);
  }
}

// ---- fused QKV: C[m][n] = xb[m,:] . Wall[n,:], coalesced epilogues ----
// Q pre-scaled by log2e/8; K natural [b,h,s,e]; V 64x64-tiled:
// Vtb[(bh*32 + s/64)*4096 + e*64 + (s%64)]
__global__ __launch_bounds__(256) void qkv_gemm(const unsigned short* __restrict__ xb,
                                                const unsigned short* __restrict__ Wall,
                                                const float* __restrict__ bq,
                                                const float* __restrict__ bk,
                                                const float* __restrict__ bv,
                                                unsigned short* __restrict__ Qb,
                                                unsigned short* __restrict__ Kb,
                                                unsigned short* __restrict__ Vtb) {
  __shared__ unsigned short As[128 * 32], Bs[128 * 32];
  __shared__ __align__(16) unsigned short Stage[4][16 * 72];  // 1152 elem/wave
  const int m0 = blockIdx.x * 128, n0 = blockIdx.y * 128;
  const int lane = threadIdx.x & 63, w = threadIdx.x >> 6;
  const int l16 = lane & 15, quad = lane >> 4;
  const int wm = w & 1, wn = w >> 1;
  const int ldrow = lane >> 2, ldcol = (lane & 3) * 8;
  const unsigned short* ga0 = xb + (size_t)(m0 + w * 32 + ldrow) * D_MODEL + ldcol;
  const unsigned short* ga1 = ga0 + 16 * D_MODEL;
  const unsigned short* gb0 = Wall + (size_t)(n0 + w * 32 + ldrow) * D_MODEL + ldcol;
  const unsigned short* gb1 = gb0 + 16 * D_MODEL;
  unsigned short* lA0 = As + (w * 2 + 0) * 512;
  unsigned short* lA1 = As + (w * 2 + 1) * 512;
  unsigned short* lB0 = Bs + (w * 2 + 0) * 512;
  unsigned short* lB1 = Bs + (w * 2 + 1) * 512;
  float4_t acc[4][4];
  float4_t z = {0.f, 0.f, 0.f, 0.f};
#pragma unroll
  for (int i = 0; i < 4; i++)
#pragma unroll
    for (int j = 0; j < 4; j++) acc[i][j] = z;
  for (int k0 = 0; k0 < D_MODEL; k0 += 32) {
    __syncthreads();
    gl_lds16(ga0 + k0, lA0);
    gl_lds16(ga1 + k0, lA1);
    gl_lds16(gb0 + k0, lB0);
    gl_lds16(gb1 + k0, lB1);
    __syncthreads();
    short8 af[4], bf[4];
#pragma unroll
    for (int i = 0; i < 4; i++) af[i] = *(const short8*)&As[(wm * 64 + i * 16 + l16) * 32 + quad * 8];
#pragma unroll
    for (int j = 0; j < 4; j++) bf[j] = *(const short8*)&Bs[(wn * 64 + j * 16 + l16) * 32 + quad * 8];
#pragma unroll
    for (int i = 0; i < 4; i++)
#pragma unroll
      for (int j = 0; j < 4; j++)
        acc[i][j] = __builtin_amdgcn_mfma_f32_16x16x32_bf16(af[i], bf[j], acc[i][j], 0, 0, 0);
  }
  const int nb = n0 + wn * 64;       // 64-aligned -> sel, h wave-uniform
  const int sel = nb >> 10;
  const int h = (nb >> 6) & 15;
  const float* bias = sel == 0 ? bq : (sel == 1 ? bk : bv);
  const int mbase = m0 + wm * 64;
  const int bb = mbase >> 11;
  const size_t bh = (size_t)(bb * N_HEADS + h);
  if (sel == 2) {
    // V: transpose 64x64 C-tile through wave-private LDS -> coalesced 16B stores
    unsigned short* vs = &Stage[w][0];
    const size_t vbase = bh * (32 * 4096) + (size_t)((mbase >> 6) & 31) * 4096;
    const int e8 = lane >> 3, ch = lane & 7;
#pragma unroll
    for (int j = 0; j < 4; j++) {
      float be = bias[h * 64 + j * 16 + l16];
#pragma unroll
      for (int i = 0; i < 4; i++)
#pragma unroll
        for (int r = 0; r < 4; r++)
          vs[l16 * 72 + i * 16 + quad * 4 + r] = f2bf(acc[i][j][r] + be);
      // wave-private, DS in-order: no barrier
#pragma unroll
      for (int rd = 0; rd < 2; rd++) {
        int er = rd * 8 + e8;
        short8 val = *(const short8*)(vs + er * 72 + ch * 8);
        *(short8*)(Vtb + vbase + (size_t)(j * 16 + er) * 64 + ch * 8) = val;
      }
    }
  } else {
    // Q/K: stage [s][e] j-slice (64x16, stride 18) in wave-private LDS -> b128 stores
    unsigned short* st = &Stage[w][0];
    unsigned short* dst = (sel == 0) ? Qb : Kb;
    const float qsc = (sel == 0) ? SC_LOG2E : 1.0f;
    const size_t rowbase = bh * SEQ + (mbase & (SEQ - 1));
    const int r2 = lane >> 1, c2 = lane & 1;
#pragma unroll
    for (int j = 0; j < 4; j++) {
      float be = bias[h * 64 + j * 16 + l16];
#pragma unroll
      for (int i = 0; i < 4; i++)
#pragma unroll
        for (int r = 0; r < 4; r++)
          st[(i * 16 + quad * 4 + r) * 18 + l16] = f2bf((acc[i][j][r] + be) * qsc);
#pragma unroll
      for (int p = 0; p < 2; p++) {
        int row = p * 32 + r2;
        short8 val = *(const short8*)(st + row * 18 + c2 * 8);
        *(short8*)(dst + (rowbase + row) * HEAD_DIM + j * 16 + c2 * 8) = val;
      }
    }
  }
}

// ---- flash attention v5: 64-row Q blocks, 4 waves x 16 rows, 3 blocks/CU ----
__global__ __launch_bounds__(256) void attn_kernel(const unsigned short* __restrict__ Q,
                                                   const unsigned short* __restrict__ K,
                                                   const unsigned short* __restrict__ Vt,
                                                   unsigned short* __restrict__ concat) {
  __shared__ __align__(16) unsigned short Ks0[64 * 72], Ks1[64 * 72];
  __shared__ __align__(16) unsigned short Vs0[64 * 72], Vs1[64 * 72];
  __shared__ __align__(16) unsigned short Ps[4][16 * 72];
  const int b = blockIdx.z, h = blockIdx.y;
  const int lane = threadIdx.x & 63, w = threadIdx.x >> 6;
  const int l16 = lane & 15, quad = lane >> 4;
  const size_t bh = (size_t)(b * N_HEADS + h);
  const int q0 = blockIdx.x * 64 + w * 16;
  float4_t z = {0.f, 0.f, 0.f, 0.f};

  short8 aq0 = *(const short8*)(Q + (bh * SEQ + q0 + l16) * HEAD_DIM + quad * 8);
  short8 aq1 = *(const short8*)(Q + (bh * SEQ + q0 + l16) * HEAD_DIM + 32 + quad * 8);

  // staging: per wave 2 KB of K (16 rows) + 2 KB of V (16 rows), contiguous global
  const int srow = lane >> 3, schk = lane & 7;
  const unsigned short* kg = K + (bh * SEQ + w * 16 + srow) * HEAD_DIM + schk * 8;
  const unsigned short* vg = Vt + bh * (32 * 4096) + (w * 16 + srow) * 64 + schk * 8;
  // K LDS row = interleave-inverse of t (so packed P writes land t-naturally)
  const int tl0 = w * 16 + srow, tl1 = tl0 + 8;
  const int kwr0 = (((tl0 >> 1) & 15) | ((tl0 & 1) << 4) | (tl0 & 32)) * 72 + schk * 8;
  const int kwr1 = (((tl1 >> 1) & 15) | ((tl1 & 1) << 4) | (tl1 & 32)) * 72 + schk * 8;
  const int vwr0 = (w * 16 + srow) * 72 + schk * 8;
  const int vwr1 = vwr0 + 8 * 72;

  float4_t o[4] = {z, z, z, z};
  float4_t ls = z;
  short8 ones;
#pragma unroll
  for (int i = 0; i < 8; i++) ones[i] = (short)0x3F80;  // bf16 1.0
  unsigned short* pb = &Ps[w][0];

  short8 kreg0 = *(const short8*)kg;
  short8 kreg1 = *(const short8*)(kg + 512);
  short8 vreg0 = *(const short8*)vg;
  short8 vreg1 = *(const short8*)(vg + 512);
  kg += 4096; vg += 4096;

  auto step = [&](unsigned short* kb, unsigned short* vb, int itv) {
    *(short8*)(kb + kwr0) = kreg0;
    *(short8*)(kb + kwr1) = kreg1;
    *(short8*)(vb + vwr0) = vreg0;
    *(short8*)(vb + vwr1) = vreg1;
    __syncthreads();
    if (itv < 31) {
      kreg0 = *(const short8*)kg;
      kreg1 = *(const short8*)(kg + 512);
      vreg0 = *(const short8*)vg;
      vreg1 = *(const short8*)(vg + 512);
      kg += 4096; vg += 4096;
    }
    float4_t s[4];
#pragma unroll
    for (int nt = 0; nt < 4; nt++) {
      short8 k0 = *(const short8*)(kb + (nt * 16 + l16) * 72 + quad * 8);
      short8 k1 = *(const short8*)(kb + (nt * 16 + l16) * 72 + 32 + quad * 8);
      s[nt] = __builtin_amdgcn_mfma_f32_16x16x32_bf16(aq0, k0, z, 0, 0, 0);
      s[nt] = __builtin_amdgcn_mfma_f32_16x16x32_bf16(aq1, k1, s[nt], 0, 0, 0);
    }
#pragma unroll
    for (int r = 0; r < 4; r++) {
      int row = quad * 4 + r;
      float p0 = __builtin_amdgcn_exp2f(s[0][r]);
      float p1 = __builtin_amdgcn_exp2f(s[1][r]);
      __hip_bfloat162 pp = __float22bfloat162_rn(float2{p0, p1});
      *(unsigned int*)(pb + row * 72 + 2 * l16) = *(unsigned int*)&pp;
      float p2 = __builtin_amdgcn_exp2f(s[2][r]);
      float p3 = __builtin_amdgcn_exp2f(s[3][r]);
      __hip_bfloat162 qq = __float22bfloat162_rn(float2{p2, p3});
      *(unsigned int*)(pb + row * 72 + 32 + 2 * l16) = *(unsigned int*)&qq;
    }
    short8 pa0 = *(const short8*)(pb + l16 * 72 + quad * 8);
    short8 pa1 = *(const short8*)(pb + l16 * 72 + 32 + quad * 8);
    ls = __builtin_amdgcn_mfma_f32_16x16x32_bf16(pa0, ones, ls, 0, 0, 0);
    ls = __builtin_amdgcn_mfma_f32_16x16x32_bf16(pa1, ones, ls, 0, 0, 0);
#pragma unroll
    for (int ne = 0; ne < 4; ne++) {
      short8 vf0 = *(const short8*)(vb + (ne * 16 + l16) * 72 + quad * 8);
      short8 vf1 = *(const short8*)(vb + (ne * 16 + l16) * 72 + 32 + quad * 8);
      o[ne] = __builtin_amdgcn_mfma_f32_16x16x32_bf16(pa0, vf0, o[ne], 0, 0, 0);
      o[ne] = __builtin_amdgcn_mfma_f32_16x16x32_bf16(pa1, vf1, o[ne], 0, 0, 0);
    }
  };

  for (int it2 = 0; it2 < 16; ++it2) {
    step(Ks0, Vs0, 2 * it2);
    step(Ks1, Vs1, 2 * it2 + 1);
  }

#pragma unroll
  for (int r = 0; r < 4; r++) {
    float li = 1.0f / ls[r];
    int sr = q0 + quad * 4 + r;
#pragma unroll
    for (int ne = 0; ne < 4; ne++)
      concat[((size_t)(b * SEQ + sr)) * D_MODEL + h * 64 + ne * 16 + l16] = f2bf(o[ne][r] * li);
  }
}

// ---- out = concat @ Wp^T + bp (f32 out), m97 structure ----
__global__ __launch_bounds__(256) void out_gemm(const unsigned short* __restrict__ cb,
                                                const unsigned short* __restrict__ Wpb,
                                                const float* __restrict__ bp,
                                                float* __restrict__ out) {
  __shared__ unsigned short As[128 * 32], Bs[128 * 32];
  const int m0 = blockIdx.x * 128, n0 = blockIdx.y * 128;
  const int lane = threadIdx.x & 63, w = threadIdx.x >> 6;
  const int l16 = lane & 15, quad = lane >> 4;
  const int wm = w & 1, wn = w >> 1;
  const int ldrow = lane >> 2, ldcol = (lane & 3) * 8;
  const unsigned short* ga0 = cb + (size_t)(m0 + w * 32 + ldrow) * D_MODEL + ldcol;
  const unsigned short* ga1 = ga0 + 16 * D_MODEL;
  const unsigned short* gb0 = Wpb + (size_t)(n0 + w * 32 + ldrow) * D_MODEL + ldcol;
  const unsigned short* gb1 = gb0 + 16 * D_MODEL;
  unsigned short* lA0 = As + (w * 2 + 0) * 512;
  unsigned short* lA1 = As + (w * 2 + 1) * 512;
  unsigned short* lB0 = Bs + (w * 2 + 0) * 512;
  unsigned short* lB1 = Bs + (w * 2 + 1) * 512;
  float4_t acc[4][4];
  float4_t z = {0.f, 0.f, 0.f, 0.f};
#pragma unroll
  for (int i = 0; i < 4; i++)
#pragma unroll
    for (int j = 0; j < 4; j++) acc[i][j] = z;
  for (int k0 = 0; k0 < D_MODEL; k0 += 32) {
    __syncthreads();
    gl_lds16(ga0 + k0, lA0);
    gl_lds16(ga1 + k0, lA1);
    gl_lds16(gb0 + k0, lB0);
    gl_lds16(gb1 + k0, lB1);
    __syncthreads();
    short8 af[4], bf[4];
#pragma unroll
    for (int i = 0; i < 4; i++) af[i] = *(const short8*)&As[(wm * 64 + i * 16 + l16) * 32 + quad * 8];
#pragma unroll
    for (int j = 0; j < 4; j++) bf[j] = *(const short8*)&Bs[(wn * 64 + j * 16 + l16) * 32 + quad * 8];
#pragma unroll
    for (int i = 0; i < 4; i++)
#pragma unroll
      for (int j = 0; j < 4; j++)
        acc[i][j] = __builtin_amdgcn_mfma_f32_16x16x32_bf16(af[i], bf[j], acc[i][j], 0, 0, 0);
  }
#pragma unroll
  for (int i = 0; i < 4; i++)
#pragma unroll
    for (int j = 0; j < 4; j++)
#pragma unroll
      for (int r = 0; r < 4; r++) {
        int m = m0 + wm * 64 + i * 16 + quad * 4 + r;
        int oc = n0 + wn * 64 + j * 16 + l16;
        out[(size_t)m * D_MODEL + oc] = acc[i][j][r] + bp[oc];
      }
}

extern "C" void kernel_launch(void* const* d_in, const int* in_sizes, int n_in,
                              void* d_out, int out_size, void* d_ws, size_t ws_size,
                              hipStream_t stream) {
  const float* x  = (const float*)d_in[0];
  const float* Wq = (const float*)d_in[1];
  const float* Wk = (const float*)d_in[2];
  const float* Wv = (const float*)d_in[3];
  const float* bq = (const float*)d_in[4];
  const float* bk = (const float*)d_in[5];
  const float* bv = (const float*)d_in[6];
  const float* Wp = (const float*)d_in[7];
  const float* bp = (const float*)d_in[8];
  float* out = (float*)d_out;

  char* ws = (char*)d_ws;
  size_t off = 0;
  auto alloc = [&](size_t bytes) -> void* {
    void* p = ws + off;
    off += (bytes + 255) & ~(size_t)255;
    return p;
  };
  unsigned short* xb   = (unsigned short*)alloc((size_t)M_ROWS * D_MODEL * 2);
  unsigned short* Wall = (unsigned short*)alloc((size_t)NQKV * D_MODEL * 2);
  unsigned short* Wpb  = (unsigned short*)alloc((size_t)D_MODEL * D_MODEL * 2);
  unsigned short* Qb   = (unsigned short*)alloc((size_t)B_SZ * N_HEADS * SEQ * HEAD_DIM * 2);
  unsigned short* Kb   = (unsigned short*)alloc((size_t)B_SZ * N_HEADS * SEQ * HEAD_DIM * 2);
  unsigned short* Vtb  = (unsigned short*)alloc((size_t)B_SZ * N_HEADS * SEQ * HEAD_DIM * 2);
  unsigned short* cbuf = (unsigned short*)alloc((size_t)B_SZ * SEQ * D_MODEL * 2);

  prep<<<17408, 256, 0, stream>>>(x, Wp, Wq, Wk, Wv, xb, Wpb, Wall);

  qkv_gemm<<<dim3(M_ROWS / 128, NQKV / 128), 256, 0, stream>>>(xb, Wall, bq, bk, bv, Qb, Kb, Vtb);

  attn_kernel<<<dim3(SEQ / 64, N_HEADS, B_SZ), 256, 0, stream>>>(Qb, Kb, Vtb, cbuf);

  out_gemm<<<dim3(M_ROWS / 128, D_MODEL / 128), 256, 0, stream>>>(cbuf, Wpb, bp, out);
}

// Round 6
// 210.063 us; speedup vs baseline: 1.0820x; 1.0820x over previous
//
#include <hip/hip_runtime.h>
#include <hip/hip_bf16.h>

typedef __attribute__((ext_vector_type(8))) short short8;
typedef __attribute__((ext_vector_type(4))) float float4_t;

#define D_MODEL 1024
#define N_HEADS 16
#define HEAD_DIM 64
#define B_SZ 2
#define SEQ 2048
#define M_ROWS (B_SZ*SEQ)   // 4096
#define NQKV 3072
#define SC_LOG2E 0.18033688011112042f  // log2(e)/sqrt(HEAD_DIM)

__device__ __forceinline__ unsigned short f2bf(float f) {
  unsigned u = __float_as_uint(f);
  u += 0x7FFFu + ((u >> 16) & 1u);   // RNE
  return (unsigned short)(u >> 16);
}

// async global->LDS, 16B per lane. LDS base must be wave-uniform.
__device__ __forceinline__ void gl_lds16(const unsigned short* g, unsigned short* l) {
  __builtin_amdgcn_global_load_lds(
      (const __attribute__((address_space(1))) unsigned int*)(size_t)g,
      (__attribute__((address_space(3))) unsigned int*)(unsigned int)(size_t)l,
      16, 0, 0);
}

// ---- fused prep: x->bf16, Wp->bf16, Wq/Wk/Wv -> Wall [sel*1024+h*64+e][d] ----
__global__ void prep(const float* __restrict__ x, const float* __restrict__ Wp,
                     const float* __restrict__ Wq, const float* __restrict__ Wk,
                     const float* __restrict__ Wv,
                     unsigned short* __restrict__ xb, unsigned short* __restrict__ Wpb,
                     unsigned short* __restrict__ Wall) {
  __shared__ float t[16][17];
  int bid = blockIdx.x;
  if (bid < 5120) {
    const float* src; unsigned short* dst; int base;
    if (bid < 4096) { src = x;  dst = xb;  base = bid * 1024 + threadIdx.x * 4; }
    else            { src = Wp; dst = Wpb; base = (bid - 4096) * 1024 + threadIdx.x * 4; }
    float4 v = *(const float4*)(src + base);
    dst[base + 0] = f2bf(v.x);
    dst[base + 1] = f2bf(v.y);
    dst[base + 2] = f2bf(v.z);
    dst[base + 3] = f2bf(v.w);
  } else {
    int u = bid - 5120;
    int sel = u >> 12;
    u &= 4095;
    const float* W = sel == 0 ? Wq : (sel == 1 ? Wk : Wv);
    int d0 = (u & 63) * 16, e0 = ((u >> 6) & 3) * 16, hh = u >> 8;
    int tx = threadIdx.x & 15, ty = threadIdx.x >> 4;
    t[ty][tx] = W[hh * (D_MODEL * HEAD_DIM) + (d0 + ty) * HEAD_DIM + e0 + tx];
    __syncthreads();
    Wall[(size_t)(sel * 1024 + hh * 64 + e0 + ty) * D_MODEL + d0 + tx] = f2bf(t[tx][ty]);
  }
}

// ---- fused QKV: C[m][n] = xb[m,:] . Wall[n,:], coalesced epilogues ----
// Q pre-scaled by log2e/8; K natural [b,h,s,e]; V 64x64-tiled:
// Vtb[(bh*32 + s/64)*4096 + e*64 + (s%64)]
__global__ __launch_bounds__(256) void qkv_gemm(const unsigned short* __restrict__ xb,
                                                const unsigned short* __restrict__ Wall,
                                                const float* __restrict__ bq,
                                                const float* __restrict__ bk,
                                                const float* __restrict__ bv,
                                                unsigned short* __restrict__ Qb,
                                                unsigned short* __restrict__ Kb,
                                                unsigned short* __restrict__ Vtb) {
  __shared__ unsigned short As[128 * 32], Bs[128 * 32];
  __shared__ __align__(16) unsigned short Stage[4][16 * 72];  // 1152 elem/wave
  const int m0 = blockIdx.x * 128, n0 = blockIdx.y * 128;
  const int lane = threadIdx.x & 63, w = threadIdx.x >> 6;
  const int l16 = lane & 15, quad = lane >> 4;
  const int wm = w & 1, wn = w >> 1;
  const int ldrow = lane >> 2, ldcol = (lane & 3) * 8;
  const unsigned short* ga0 = xb + (size_t)(m0 + w * 32 + ldrow) * D_MODEL + ldcol;
  const unsigned short* ga1 = ga0 + 16 * D_MODEL;
  const unsigned short* gb0 = Wall + (size_t)(n0 + w * 32 + ldrow) * D_MODEL + ldcol;
  const unsigned short* gb1 = gb0 + 16 * D_MODEL;
  unsigned short* lA0 = As + (w * 2 + 0) * 512;
  unsigned short* lA1 = As + (w * 2 + 1) * 512;
  unsigned short* lB0 = Bs + (w * 2 + 0) * 512;
  unsigned short* lB1 = Bs + (w * 2 + 1) * 512;
  float4_t acc[4][4];
  float4_t z = {0.f, 0.f, 0.f, 0.f};
#pragma unroll
  for (int i = 0; i < 4; i++)
#pragma unroll
    for (int j = 0; j < 4; j++) acc[i][j] = z;
  for (int k0 = 0; k0 < D_MODEL; k0 += 32) {
    __syncthreads();
    gl_lds16(ga0 + k0, lA0);
    gl_lds16(ga1 + k0, lA1);
    gl_lds16(gb0 + k0, lB0);
    gl_lds16(gb1 + k0, lB1);
    __syncthreads();
    short8 af[4], bf[4];
#pragma unroll
    for (int i = 0; i < 4; i++) af[i] = *(const short8*)&As[(wm * 64 + i * 16 + l16) * 32 + quad * 8];
#pragma unroll
    for (int j = 0; j < 4; j++) bf[j] = *(const short8*)&Bs[(wn * 64 + j * 16 + l16) * 32 + quad * 8];
#pragma unroll
    for (int i = 0; i < 4; i++)
#pragma unroll
      for (int j = 0; j < 4; j++)
        acc[i][j] = __builtin_amdgcn_mfma_f32_16x16x32_bf16(af[i], bf[j], acc[i][j], 0, 0, 0);
  }
  const int nb = n0 + wn * 64;       // 64-aligned -> sel, h wave-uniform
  const int sel = nb >> 10;
  const int h = (nb >> 6) & 15;
  const float* bias = sel == 0 ? bq : (sel == 1 ? bk : bv);
  const int mbase = m0 + wm * 64;
  const int bb = mbase >> 11;
  const size_t bh = (size_t)(bb * N_HEADS + h);
  if (sel == 2) {
    // V: transpose 64x64 C-tile through wave-private LDS -> coalesced 16B stores
    unsigned short* vs = &Stage[w][0];
    const size_t vbase = bh * (32 * 4096) + (size_t)((mbase >> 6) & 31) * 4096;
    const int e8 = lane >> 3, ch = lane & 7;
#pragma unroll
    for (int j = 0; j < 4; j++) {
      float be = bias[h * 64 + j * 16 + l16];
#pragma unroll
      for (int i = 0; i < 4; i++)
#pragma unroll
        for (int r = 0; r < 4; r++)
          vs[l16 * 72 + i * 16 + quad * 4 + r] = f2bf(acc[i][j][r] + be);
      // wave-private, DS in-order: no barrier
#pragma unroll
      for (int rd = 0; rd < 2; rd++) {
        int er = rd * 8 + e8;
        short8 val = *(const short8*)(vs + er * 72 + ch * 8);
        *(short8*)(Vtb + vbase + (size_t)(j * 16 + er) * 64 + ch * 8) = val;
      }
    }
  } else {
    // Q/K: stage [s][e] j-slice (64x16, stride 18) in wave-private LDS -> b128 stores
    unsigned short* st = &Stage[w][0];
    unsigned short* dst = (sel == 0) ? Qb : Kb;
    const float qsc = (sel == 0) ? SC_LOG2E : 1.0f;
    const size_t rowbase = bh * SEQ + (mbase & (SEQ - 1));
    const int r2 = lane >> 1, c2 = lane & 1;
#pragma unroll
    for (int j = 0; j < 4; j++) {
      float be = bias[h * 64 + j * 16 + l16];
#pragma unroll
      for (int i = 0; i < 4; i++)
#pragma unroll
        for (int r = 0; r < 4; r++)
          st[(i * 16 + quad * 4 + r) * 18 + l16] = f2bf((acc[i][j][r] + be) * qsc);
#pragma unroll
      for (int p = 0; p < 2; p++) {
        int row = p * 32 + r2;
        short8 val = *(const short8*)(st + row * 18 + c2 * 8);
        *(short8*)(dst + (rowbase + row) * HEAD_DIM + j * 16 + c2 * 8) = val;
      }
    }
  }
}

// ---- flash attention v6: round-4 shape (128-row blocks, 32 Q-rows/wave),
// Ps stride 64 -> LDS 53248 B -> 3 blocks/CU ----
__global__ __launch_bounds__(256) void attn_kernel(const unsigned short* __restrict__ Q,
                                                   const unsigned short* __restrict__ K,
                                                   const unsigned short* __restrict__ Vt,
                                                   unsigned short* __restrict__ concat) {
  __shared__ __align__(16) unsigned short Ks0[64 * 72], Ks1[64 * 72];
  __shared__ __align__(16) unsigned short Vs0[64 * 72], Vs1[64 * 72];
  __shared__ __align__(16) unsigned short Ps[4][32 * 64];
  const int b = blockIdx.z, h = blockIdx.y;
  const int lane = threadIdx.x & 63, w = threadIdx.x >> 6;
  const int l16 = lane & 15, quad = lane >> 4;
  const size_t bh = (size_t)(b * N_HEADS + h);
  const int q0 = blockIdx.x * 128 + w * 32;
  float4_t z = {0.f, 0.f, 0.f, 0.f};

  short8 aq[2][2];
#pragma unroll
  for (int rg = 0; rg < 2; rg++)
#pragma unroll
    for (int hf = 0; hf < 2; hf++)
      aq[rg][hf] = *(const short8*)(Q + (bh * SEQ + q0 + rg * 16 + l16) * HEAD_DIM + hf * 32 + quad * 8);

  const int srow = lane >> 3, schk = lane & 7;
  const unsigned short* kg = K + (bh * SEQ + w * 16 + srow) * HEAD_DIM + schk * 8;
  const unsigned short* vg = Vt + bh * (32 * 4096) + (w * 16 + srow) * 64 + schk * 8;
  const int tl0 = w * 16 + srow, tl1 = tl0 + 8;
  const int kwr0 = (((tl0 >> 1) & 15) | ((tl0 & 1) << 4) | (tl0 & 32)) * 72 + schk * 8;
  const int kwr1 = (((tl1 >> 1) & 15) | ((tl1 & 1) << 4) | (tl1 & 32)) * 72 + schk * 8;
  const int vwr0 = (w * 16 + srow) * 72 + schk * 8;
  const int vwr1 = vwr0 + 8 * 72;

  float4_t o[2][4];
  float4_t ls[2] = {z, z};
#pragma unroll
  for (int rg = 0; rg < 2; rg++)
#pragma unroll
    for (int ne = 0; ne < 4; ne++) o[rg][ne] = z;
  short8 ones;
#pragma unroll
  for (int i = 0; i < 8; i++) ones[i] = (short)0x3F80;  // bf16 1.0
  unsigned short* pb = &Ps[w][0];

  short8 kreg0 = *(const short8*)kg;
  short8 kreg1 = *(const short8*)(kg + 512);
  short8 vreg0 = *(const short8*)vg;
  short8 vreg1 = *(const short8*)(vg + 512);
  kg += 4096; vg += 4096;

  auto step = [&](unsigned short* kb, unsigned short* vb, int itv) {
    *(short8*)(kb + kwr0) = kreg0;
    *(short8*)(kb + kwr1) = kreg1;
    *(short8*)(vb + vwr0) = vreg0;
    *(short8*)(vb + vwr1) = vreg1;
    __syncthreads();
    if (itv < 31) {
      kreg0 = *(const short8*)kg;
      kreg1 = *(const short8*)(kg + 512);
      vreg0 = *(const short8*)vg;
      vreg1 = *(const short8*)(vg + 512);
      kg += 4096; vg += 4096;
    }
    float4_t s[2][4];
#pragma unroll
    for (int nt = 0; nt < 4; nt++) {
      short8 k0 = *(const short8*)(kb + (nt * 16 + l16) * 72 + quad * 8);
      short8 k1 = *(const short8*)(kb + (nt * 16 + l16) * 72 + 32 + quad * 8);
      s[0][nt] = __builtin_amdgcn_mfma_f32_16x16x32_bf16(aq[0][0], k0, z, 0, 0, 0);
      s[0][nt] = __builtin_amdgcn_mfma_f32_16x16x32_bf16(aq[0][1], k1, s[0][nt], 0, 0, 0);
      s[1][nt] = __builtin_amdgcn_mfma_f32_16x16x32_bf16(aq[1][0], k0, z, 0, 0, 0);
      s[1][nt] = __builtin_amdgcn_mfma_f32_16x16x32_bf16(aq[1][1], k1, s[1][nt], 0, 0, 0);
    }
#pragma unroll
    for (int rg = 0; rg < 2; rg++) {
#pragma unroll
      for (int r = 0; r < 4; r++) {
        int row = rg * 16 + quad * 4 + r;
        float p0 = __builtin_amdgcn_exp2f(s[rg][0][r]);
        float p1 = __builtin_amdgcn_exp2f(s[rg][1][r]);
        __hip_bfloat162 pp = __float22bfloat162_rn(float2{p0, p1});
        *(unsigned int*)(pb + row * 64 + 2 * l16) = *(unsigned int*)&pp;
        float p2 = __builtin_amdgcn_exp2f(s[rg][2][r]);
        float p3 = __builtin_amdgcn_exp2f(s[rg][3][r]);
        __hip_bfloat162 qq = __float22bfloat162_rn(float2{p2, p3});
        *(unsigned int*)(pb + row * 64 + 32 + 2 * l16) = *(unsigned int*)&qq;
      }
    }
    short8 pa[2][2];
#pragma unroll
    for (int rg = 0; rg < 2; rg++)
#pragma unroll
      for (int hf = 0; hf < 2; hf++)
        pa[rg][hf] = *(const short8*)(pb + (rg * 16 + l16) * 64 + hf * 32 + quad * 8);
#pragma unroll
    for (int rg = 0; rg < 2; rg++) {
      ls[rg] = __builtin_amdgcn_mfma_f32_16x16x32_bf16(pa[rg][0], ones, ls[rg], 0, 0, 0);
      ls[rg] = __builtin_amdgcn_mfma_f32_16x16x32_bf16(pa[rg][1], ones, ls[rg], 0, 0, 0);
    }
#pragma unroll
    for (int ne = 0; ne < 4; ne++) {
#pragma unroll
      for (int hf = 0; hf < 2; hf++) {
        short8 vf = *(const short8*)(vb + (ne * 16 + l16) * 72 + hf * 32 + quad * 8);
        o[0][ne] = __builtin_amdgcn_mfma_f32_16x16x32_bf16(pa[0][hf], vf, o[0][ne], 0, 0, 0);
        o[1][ne] = __builtin_amdgcn_mfma_f32_16x16x32_bf16(pa[1][hf], vf, o[1][ne], 0, 0, 0);
      }
    }
  };

  for (int it2 = 0; it2 < 16; ++it2) {
    step(Ks0, Vs0, 2 * it2);
    step(Ks1, Vs1, 2 * it2 + 1);
  }

#pragma unroll
  for (int rg = 0; rg < 2; rg++) {
#pragma unroll
    for (int r = 0; r < 4; r++) {
      float li = 1.0f / ls[rg][r];
      int sr = q0 + rg * 16 + quad * 4 + r;
#pragma unroll
      for (int ne = 0; ne < 4; ne++)
        concat[((size_t)(b * SEQ + sr)) * D_MODEL + h * 64 + ne * 16 + l16] = f2bf(o[rg][ne][r] * li);
    }
  }
}

// ---- out = concat @ Wp^T + bp (f32 out), 128x64 tiles -> 512 blocks ----
__global__ __launch_bounds__(256) void out_gemm(const unsigned short* __restrict__ cb,
                                                const unsigned short* __restrict__ Wpb,
                                                const float* __restrict__ bp,
                                                float* __restrict__ out) {
  __shared__ unsigned short As[128 * 32], Bs[64 * 32];
  const int m0 = blockIdx.x * 128, n0 = blockIdx.y * 64;
  const int lane = threadIdx.x & 63, w = threadIdx.x >> 6;
  const int l16 = lane & 15, quad = lane >> 4;
  const int ldrow = lane >> 2, ldcol = (lane & 3) * 8;
  const unsigned short* ga0 = cb + (size_t)(m0 + w * 32 + ldrow) * D_MODEL + ldcol;
  const unsigned short* ga1 = ga0 + 16 * D_MODEL;
  const unsigned short* gb0 = Wpb + (size_t)(n0 + w * 16 + ldrow) * D_MODEL + ldcol;
  unsigned short* lA0 = As + (w * 2 + 0) * 512;
  unsigned short* lA1 = As + (w * 2 + 1) * 512;
  unsigned short* lB0 = Bs + w * 512;
  float4_t acc[2][4];
  float4_t z = {0.f, 0.f, 0.f, 0.f};
#pragma unroll
  for (int i = 0; i < 2; i++)
#pragma unroll
    for (int j = 0; j < 4; j++) acc[i][j] = z;
  for (int k0 = 0; k0 < D_MODEL; k0 += 32) {
    __syncthreads();
    gl_lds16(ga0 + k0, lA0);
    gl_lds16(ga1 + k0, lA1);
    gl_lds16(gb0 + k0, lB0);
    __syncthreads();
    short8 af[2], bf[4];
#pragma unroll
    for (int i = 0; i < 2; i++) af[i] = *(const short8*)&As[(w * 32 + i * 16 + l16) * 32 + quad * 8];
#pragma unroll
    for (int j = 0; j < 4; j++) bf[j] = *(const short8*)&Bs[(j * 16 + l16) * 32 + quad * 8];
#pragma unroll
    for (int i = 0; i < 2; i++)
#pragma unroll
      for (int j = 0; j < 4; j++)
        acc[i][j] = __builtin_amdgcn_mfma_f32_16x16x32_bf16(af[i], bf[j], acc[i][j], 0, 0, 0);
  }
#pragma unroll
  for (int i = 0; i < 2; i++)
#pragma unroll
    for (int j = 0; j < 4; j++)
#pragma unroll
      for (int r = 0; r < 4; r++) {
        int m = m0 + w * 32 + i * 16 + quad * 4 + r;
        int oc = n0 + j * 16 + l16;
        out[(size_t)m * D_MODEL + oc] = acc[i][j][r] + bp[oc];
      }
}

extern "C" void kernel_launch(void* const* d_in, const int* in_sizes, int n_in,
                              void* d_out, int out_size, void* d_ws, size_t ws_size,
                              hipStream_t stream) {
  const float* x  = (const float*)d_in[0];
  const float* Wq = (const float*)d_in[1];
  const float* Wk = (const float*)d_in[2];
  const float* Wv = (const float*)d_in[3];
  const float* bq = (const float*)d_in[4];
  const float* bk = (const float*)d_in[5];
  const float* bv = (const float*)d_in[6];
  const float* Wp = (const float*)d_in[7];
  const float* bp = (const float*)d_in[8];
  float* out = (float*)d_out;

  char* ws = (char*)d_ws;
  size_t off = 0;
  auto alloc = [&](size_t bytes) -> void* {
    void* p = ws + off;
    off += (bytes + 255) & ~(size_t)255;
    return p;
  };
  unsigned short* xb   = (unsigned short*)alloc((size_t)M_ROWS * D_MODEL * 2);
  unsigned short* Wall = (unsigned short*)alloc((size_t)NQKV * D_MODEL * 2);
  unsigned short* Wpb  = (unsigned short*)alloc((size_t)D_MODEL * D_MODEL * 2);
  unsigned short* Qb   = (unsigned short*)alloc((size_t)B_SZ * N_HEADS * SEQ * HEAD_DIM * 2);
  unsigned short* Kb   = (unsigned short*)alloc((size_t)B_SZ * N_HEADS * SEQ * HEAD_DIM * 2);
  unsigned short* Vtb  = (unsigned short*)alloc((size_t)B_SZ * N_HEADS * SEQ * HEAD_DIM * 2);
  unsigned short* cbuf = (unsigned short*)alloc((size_t)B_SZ * SEQ * D_MODEL * 2);

  prep<<<17408, 256, 0, stream>>>(x, Wp, Wq, Wk, Wv, xb, Wpb, Wall);

  qkv_gemm<<<dim3(M_ROWS / 128, NQKV / 128), 256, 0, stream>>>(xb, Wall, bq, bk, bv, Qb, Kb, Vtb);

  attn_kernel<<<dim3(SEQ / 128, N_HEADS, B_SZ), 256, 0, stream>>>(Qb, Kb, Vtb, cbuf);

  out_gemm<<<dim3(M_ROWS / 128, D_MODEL / 64), 256, 0, stream>>>(cbuf, Wpb, bp, out);
}